// Round 11
// baseline (223.624 us; speedup 1.0000x reference)
//
#include <hip/hip_runtime.h>
#include <hip/hip_fp16.h>
#include <stdint.h>

// VM-factorized voxel grid: N pts -> 48 feats (3 planes x 16ch) -> 27 outputs.
// Pipeline: memset hist(4096) -> prep (planes/lines -> fp16 channel-last, basis
// B-frags, 16^3 hist with 32768-pt blocks) -> scan -> scatter (two-pass LDS rank,
// ~128B runs) -> eval: one block per cell, plane patches staged in LDS (22x22x16ch
// fp16 x3 = 46.5KB), ds_read gathers, fp16 interp, 3x mfma_f32_32x32x16_f16,
// direct coalesced stores from MFMA fragments with ragged-tail predication.

constexpr int NPTS = 2097152;
constexpr int CCH  = 16;
constexpr int RES  = 320;
constexpr long long HW = (long long)RES * RES;   // 102400
constexpr int FD   = 27;
constexpr int BLK  = 256;
constexpr int CDIM = 16;
constexpr int NCELL = CDIM * CDIM * CDIM;        // 4096
constexpr int PATCH = 22;                        // texels per patch axis
constexpr int PP_U4 = PATCH * PATCH * 2;         // 968 uint4 per plane patch
constexpr int PL_U4 = 3 * PP_U4;                 // 2904
constexpr int LN_U4 = 3 * PATCH * 2;             // 132
constexpr int SORT_BLOCKS = 64;
constexpr int PTS_PER_SORT = NPTS / SORT_BLOCKS; // 32768

constexpr int PLANE_BLOCKS = 1200;               // 3 * 400
constexpr int LINE_BLOCKS = 4;

// ---- workspace layout (bytes), all 16B-aligned ----
constexpr size_t WS_PLANEH = 0;                                   // 9,830,400
constexpr size_t WS_LINEH  = WS_PLANEH + 3ull*HW*CCH*2;           // 30,720
constexpr size_t WS_BFRAG  = WS_LINEH + 3ull*RES*CCH*2;           // 3,072
constexpr size_t WS_CHIST  = WS_BFRAG + 3072;                     // 16,384
constexpr size_t WS_CURSOR = WS_CHIST + (size_t)NCELL*4;          // 16,384
constexpr size_t WS_SORTED = WS_CURSOR + (size_t)NCELL*4;         // N*16
constexpr size_t WS_NEED   = WS_SORTED + (size_t)NPTS*16;         // ~43.5 MB

typedef _Float16 half8 __attribute__((ext_vector_type(8)));
typedef float f32x16 __attribute__((ext_vector_type(16)));

// ---------------- helpers ----------------
__device__ __forceinline__ int cell_key16(float px, float py, float pz) {
    int cx = min(max((int)((px + 1.f) * 8.f), 0), 15);
    int cy = min(max((int)((py + 1.f) * 8.f), 0), 15);
    int cz = min(max((int)((pz + 1.f) * 8.f), 0), 15);
    return (cz << 8) | (cy << 4) | cx;
}

// ---------------- prep: hist (128 pts/thread, LDS) + planes/lines fp16 + basis B-frags ----------------
__global__ __launch_bounds__(BLK) void prep_kernel(
    const float* __restrict__ pts,
    const float* __restrict__ pxy, const float* __restrict__ pxz, const float* __restrict__ pyz,
    const float* __restrict__ vx, const float* __restrict__ vy, const float* __restrict__ vz,
    const float* __restrict__ basis,
    __half* __restrict__ planesH, __half* __restrict__ linesH, __half* __restrict__ bfragH,
    unsigned* __restrict__ chist) {
    __shared__ unsigned lh[NCELL];
    const int bid = blockIdx.x;
    const int tid = threadIdx.x;
    if (bid < SORT_BLOCKS) {                // histogram, 32768 pts/block
        #pragma unroll
        for (int k = 0; k < NCELL / BLK; ++k) lh[tid + k * BLK] = 0u;
        __syncthreads();
        const float4* p4 = ((const float4*)pts) + (size_t)bid * (PTS_PER_SORT * 3 / 4);
        for (int g = 0; g < 32; ++g) {
            const int t = g * BLK + tid;
            const float4 a = p4[t*3+0], b = p4[t*3+1], c = p4[t*3+2];
            atomicAdd(&lh[cell_key16(a.x, a.y, a.z)], 1u);
            atomicAdd(&lh[cell_key16(a.w, b.x, b.y)], 1u);
            atomicAdd(&lh[cell_key16(b.z, b.w, c.x)], 1u);
            atomicAdd(&lh[cell_key16(c.y, c.z, c.w)], 1u);
        }
        __syncthreads();
        #pragma unroll
        for (int k = 0; k < NCELL / BLK; ++k) {
            const int i = tid + k * BLK;
            if (lh[i]) atomicAdd(&chist[i], lh[i]);
        }
    } else if (bid < SORT_BLOCKS + PLANE_BLOCKS) {   // planes -> fp16 channel-last
        const int pb = bid - SORT_BLOCKS;
        const int plane = pb / 400;
        const int texel = (pb % 400) * BLK + tid;
        const float* src = (plane == 0) ? pxy : (plane == 1 ? pxz : pyz);
        union { ushort u[16]; uint4 q[2]; } pk;
        #pragma unroll
        for (int c = 0; c < CCH; ++c)
            pk.u[c] = __half_as_ushort(__float2half(src[(size_t)c * HW + texel]));
        uint4* dst = (uint4*)(planesH + ((size_t)plane * HW + texel) * CCH);
        dst[0] = pk.q[0]; dst[1] = pk.q[1];
    } else if (bid < SORT_BLOCKS + PLANE_BLOCKS + LINE_BLOCKS) {  // lines
        const int idx = (bid - SORT_BLOCKS - PLANE_BLOCKS) * BLK + tid;
        if (idx >= 3 * RES) return;
        const int axis = idx / RES, t = idx % RES;
        const float* src = (axis == 0) ? vx : (axis == 1 ? vy : vz);
        union { ushort u[16]; uint4 q[2]; } pk;
        #pragma unroll
        for (int c = 0; c < CCH; ++c)
            pk.u[c] = __half_as_ushort(__float2half(src[c * RES + t]));
        uint4* dst = (uint4*)(linesH + ((size_t)axis * RES + t) * CCH);
        dst[0] = pk.q[0]; dst[1] = pk.q[1];
    } else {   // basis (48,27) -> MFMA B-frag fp16
        if (tid < 192) {
            const int r = tid >> 6, l = tid & 63;
            const int col = l & 31, kb = l >> 5;
            __half* dst = bfragH + tid * 8;
            #pragma unroll
            for (int j = 0; j < 8; ++j) {
                float v = (col < FD) ? basis[(r * 16 + kb * 8 + j) * FD + col] : 0.f;
                dst[j] = __float2half(v);
            }
        }
    }
}

// ---------------- scan: exclusive scan of 4096 counts -> cursor ----------------
__global__ __launch_bounds__(1024) void scan_kernel(const unsigned* __restrict__ chist,
                                                    unsigned* __restrict__ cursor) {
    __shared__ unsigned lsum[1024];
    const int t = threadIdx.x;
    const uint4 v = ((const uint4*)chist)[t];
    const unsigned run = v.x + v.y + v.z + v.w;
    lsum[t] = run;
    __syncthreads();
    for (int o = 1; o < 1024; o <<= 1) {
        unsigned u = (t >= o) ? lsum[t - o] : 0u;
        __syncthreads();
        lsum[t] += u;
        __syncthreads();
    }
    const unsigned b = lsum[t] - run;
    ((uint4*)cursor)[t] = make_uint4(b, b + v.x, b + v.x + v.y, b + v.x + v.y + v.z);
}

// ---------------- scatter: two-pass LDS rank + 1 global atomic per (block,cell) ----------------
__global__ __launch_bounds__(BLK) void scatter_kernel(const float* __restrict__ pts,
                                                      unsigned* __restrict__ cursor,
                                                      float4* __restrict__ sorted) {
    __shared__ unsigned lh[NCELL];
    __shared__ unsigned lh2[NCELL];
    __shared__ unsigned lb[NCELL];
    const int bid = blockIdx.x;
    const int tid = threadIdx.x;
    #pragma unroll
    for (int k = 0; k < NCELL / BLK; ++k) { lh[tid + k*BLK] = 0u; lh2[tid + k*BLK] = 0u; }
    __syncthreads();
    const float4* p4 = ((const float4*)pts) + (size_t)bid * (PTS_PER_SORT * 3 / 4);
    for (int g = 0; g < 32; ++g) {           // pass 1: count
        const int t = g * BLK + tid;
        const float4 a = p4[t*3+0], b = p4[t*3+1], c = p4[t*3+2];
        atomicAdd(&lh[cell_key16(a.x, a.y, a.z)], 1u);
        atomicAdd(&lh[cell_key16(a.w, b.x, b.y)], 1u);
        atomicAdd(&lh[cell_key16(b.z, b.w, c.x)], 1u);
        atomicAdd(&lh[cell_key16(c.y, c.z, c.w)], 1u);
    }
    __syncthreads();
    #pragma unroll
    for (int k = 0; k < NCELL / BLK; ++k) {  // claim contiguous runs
        const int i = tid + k * BLK;
        lb[i] = lh[i] ? atomicAdd(&cursor[i], lh[i]) : 0u;
    }
    __syncthreads();
    const int ibase = bid * PTS_PER_SORT;
    for (int g = 0; g < 32; ++g) {           // pass 2: rank + place
        const int t = g * BLK + tid;
        const float4 a = p4[t*3+0], b = p4[t*3+1], c = p4[t*3+2];
        const int i0 = ibase + t * 4;
        int k; unsigned r;
        k = cell_key16(a.x, a.y, a.z); r = atomicAdd(&lh2[k], 1u);
        sorted[lb[k] + r] = make_float4(a.x, a.y, a.z, __int_as_float(i0 + 0));
        k = cell_key16(a.w, b.x, b.y); r = atomicAdd(&lh2[k], 1u);
        sorted[lb[k] + r] = make_float4(a.w, b.x, b.y, __int_as_float(i0 + 1));
        k = cell_key16(b.z, b.w, c.x); r = atomicAdd(&lh2[k], 1u);
        sorted[lb[k] + r] = make_float4(b.z, b.w, c.x, __int_as_float(i0 + 2));
        k = cell_key16(c.y, c.z, c.w); r = atomicAdd(&lh2[k], 1u);
        sorted[lb[k] + r] = make_float4(c.y, c.z, c.w, __int_as_float(i0 + 3));
    }
}

// ---------------- eval ----------------
// All interp reads from LDS patch. Indices are uint4 offsets into s_patch (h folded in).
__device__ __forceinline__ half8 interp8_lds(const uint4* __restrict__ sp,
                                             int i00, int i01, int i10, int i11,
                                             int il0, int il1,
                                             float wc, float wr, float lw) {
    union U { uint4 u; __half2 h2[4]; half8 v; };
    U c00, c01, c10, c11, la, lb, res;
    c00.u = sp[i00]; c01.u = sp[i01];
    c10.u = sp[i10]; c11.u = sp[i11];
    la.u  = sp[il0]; lb.u  = sp[il1];
    const float w00 = (1.f - wc) * (1.f - wr), w01 = wc * (1.f - wr);
    const float w10 = (1.f - wc) * wr,         w11 = wc * wr;
    const __half2 w00h = __float2half2_rn(w00), w01h = __float2half2_rn(w01);
    const __half2 w10h = __float2half2_rn(w10), w11h = __float2half2_rn(w11);
    const __half2 lwh  = __float2half2_rn(lw),  mlwh = __float2half2_rn(1.f - lw);
    #pragma unroll
    for (int q = 0; q < 4; ++q) {
        __half2 s = __hmul2(c00.h2[q], w00h);
        s = __hfma2(c01.h2[q], w01h, s);
        s = __hfma2(c10.h2[q], w10h, s);
        s = __hfma2(c11.h2[q], w11h, s);
        __half2 l = __hmul2(la.h2[q], mlwh);
        l = __hfma2(lb.h2[q], lwh, l);
        res.h2[q] = __hmul2(s, l);
    }
    return res.v;
}

__global__ __launch_bounds__(BLK) void eval_kernel(
    const float4* __restrict__ sorted,
    const __half* __restrict__ planesH,
    const __half* __restrict__ linesH,
    const __half* __restrict__ bfragH,
    const unsigned* __restrict__ chist,
    const unsigned* __restrict__ cursor,
    float* __restrict__ out) {
    __shared__ uint4 s_patch[PL_U4 + LN_U4];     // 48,576 B
    __shared__ int s_oi[BLK];                    // 1 KB
    const int bid = blockIdx.x;
    const int tid = threadIdx.x;
    const int cell = (bid & 7) * (NCELL / 8) + (bid >> 3);   // contiguous cells per XCD
    const int cx = cell & 15, cy = (cell >> 4) & 15, cz = cell >> 8;
    const int bx = (cx * 319) >> 4, by = (cy * 319) >> 4, bz = (cz * 319) >> 4;

    // stage plane patches (22x22 texels x 16ch fp16 each)
    for (int i = tid; i < PL_U4; i += BLK) {
        const int p = i / PP_U4, rem = i - p * PP_U4;
        const int r = rem / 44, c4 = rem - r * 44;
        const int tx = c4 >> 1, h = c4 & 1;
        const int rb = (p == 0) ? by : bz;
        const int cb = (p == 2) ? by : bx;
        const int gr = min(rb + r, RES - 1), gc = min(cb + tx, RES - 1);
        s_patch[i] = ((const uint4*)(planesH + ((size_t)p * HW + (size_t)gr * RES + gc) * CCH))[h];
    }
    // stage line segments (22 entries x 16ch each)
    for (int i = tid; i < LN_U4; i += BLK) {
        const int a = i / 44, rem = i - a * 44;
        const int t = rem >> 1, h = rem & 1;
        const int ab = (a == 0) ? bx : (a == 1) ? by : bz;
        const int gt = min(ab + t, RES - 1);
        s_patch[PL_U4 + i] = ((const uint4*)(linesH + ((size_t)a * RES + gt) * CCH))[h];
    }

    const int wid = tid >> 6, lane = tid & 63;
    const int pcol = lane & 31, kb = lane >> 5;
    union BU { uint4 u; half8 h; } b0u, b1u, b2u;
    const uint4* bf = (const uint4*)bfragH;
    b0u.u = bf[lane]; b1u.u = bf[64 + lane]; b2u.u = bf[128 + lane];

    __syncthreads();

    const int cnt = (int)chist[cell];
    const int start = (int)cursor[cell] - cnt;   // cursor holds end offsets post-scatter

    for (int base = 0; base < cnt; base += BLK) {
        #pragma unroll
        for (int t = 0; t < 2; ++t) {
            const int tb = wid * 64 + t * 32;
            if (base + tb < cnt) {
                const int slot = base + tb + pcol;
                const float4 pt = sorted[start + min(slot, cnt - 1)];
                if (kb == 0) s_oi[tb + pcol] = __float_as_int(pt.w);

                const float scl = 0.5f * (RES - 1);
                const float fx = (pt.x + 1.f) * scl, fy = (pt.y + 1.f) * scl, fz = (pt.z + 1.f) * scl;
                const float xf = floorf(fx), yf = floorf(fy), zf = floorf(fz);
                const float wx = fx - xf, wy = fy - yf, wz = fz - zf;
                int x0 = min(max((int)xf, 0), RES - 1);
                int y0 = min(max((int)yf, 0), RES - 1);
                int z0 = min(max((int)zf, 0), RES - 1);
                const int x1 = min(x0 + 1, RES - 1);
                const int y1 = min(y0 + 1, RES - 1);
                const int z1 = min(z0 + 1, RES - 1);
                const int lx0 = x0 - bx, lx1 = x1 - bx;
                const int ly0 = y0 - by, ly1 = y1 - by;
                const int lz0 = z0 - bz, lz1 = z1 - bz;

                f32x16 acc;
                #pragma unroll
                for (int r = 0; r < 16; ++r) acc[r] = 0.f;

                // plane xy (rows y, cols x) * line z
                half8 a0 = interp8_lds(s_patch,
                    (ly0*PATCH + lx0)*2 + kb, (ly0*PATCH + lx1)*2 + kb,
                    (ly1*PATCH + lx0)*2 + kb, (ly1*PATCH + lx1)*2 + kb,
                    PL_U4 + 2*44 + lz0*2 + kb, PL_U4 + 2*44 + lz1*2 + kb, wx, wy, wz);
                acc = __builtin_amdgcn_mfma_f32_32x32x16_f16(a0, b0u.h, acc, 0, 0, 0);
                // plane xz (rows z, cols x) * line y
                half8 a1 = interp8_lds(s_patch,
                    PP_U4 + (lz0*PATCH + lx0)*2 + kb, PP_U4 + (lz0*PATCH + lx1)*2 + kb,
                    PP_U4 + (lz1*PATCH + lx0)*2 + kb, PP_U4 + (lz1*PATCH + lx1)*2 + kb,
                    PL_U4 + 1*44 + ly0*2 + kb, PL_U4 + 1*44 + ly1*2 + kb, wx, wz, wy);
                acc = __builtin_amdgcn_mfma_f32_32x32x16_f16(a1, b1u.h, acc, 0, 0, 0);
                // plane yz (rows z, cols y) * line x
                half8 a2 = interp8_lds(s_patch,
                    2*PP_U4 + (lz0*PATCH + ly0)*2 + kb, 2*PP_U4 + (lz0*PATCH + ly1)*2 + kb,
                    2*PP_U4 + (lz1*PATCH + ly0)*2 + kb, 2*PP_U4 + (lz1*PATCH + ly1)*2 + kb,
                    PL_U4 + 0*44 + lx0*2 + kb, PL_U4 + 0*44 + lx1*2 + kb, wy, wz, wx);
                acc = __builtin_amdgcn_mfma_f32_32x32x16_f16(a2, b2u.h, acc, 0, 0, 0);

                // direct coalesced stores: D col(=feature)=lane&31, row(=point)=(r&3)+8*(r>>2)+4*kb
                if (pcol < FD) {
                    #pragma unroll
                    for (int r = 0; r < 16; ++r) {
                        const int row = (r & 3) + 8 * (r >> 2) + 4 * kb;
                        if (base + tb + row < cnt) {
                            const int o = s_oi[tb + row];
                            out[(size_t)o * FD + pcol] = acc[r];
                        }
                    }
                }
            }
        }
    }
}

// ---------------- fallback (no workspace) ----------------
__device__ __forceinline__ float bilerp(const float* __restrict__ p,
                                        int o00, int o01, int o10, int o11,
                                        float wc, float wr) {
    float v00 = p[o00], v01 = p[o01], v10 = p[o10], v11 = p[o11];
    float top = v00 + wc * (v01 - v00);
    float bot = v10 + wc * (v11 - v10);
    return top + wr * (bot - top);
}

__global__ __launch_bounds__(BLK) void vm_eval_fallback(
    const float* __restrict__ pts,
    const float* __restrict__ pxy, const float* __restrict__ pyz, const float* __restrict__ pxz,
    const float* __restrict__ vx, const float* __restrict__ vy, const float* __restrict__ vz,
    const float* __restrict__ basis, float* __restrict__ out) {
    const long long i = (long long)blockIdx.x * BLK + threadIdx.x;
    const float px = pts[i*3], py = pts[i*3+1], pz = pts[i*3+2];
    const float scl = 0.5f * (RES - 1);
    const float fx = (px + 1.f) * scl, fy = (py + 1.f) * scl, fz = (pz + 1.f) * scl;
    const float xf = floorf(fx), yf = floorf(fy), zf = floorf(fz);
    const float wx = fx - xf, wy = fy - yf, wz = fz - zf;
    int x0 = min(max((int)xf, 0), RES - 1);
    int y0 = min(max((int)yf, 0), RES - 1);
    int z0 = min(max((int)zf, 0), RES - 1);
    const int x1 = min(x0+1, RES-1), y1 = min(y0+1, RES-1), z1 = min(z0+1, RES-1);
    float acc[FD];
    #pragma unroll
    for (int f = 0; f < FD; ++f) acc[f] = 0.f;
    #pragma unroll 4
    for (int c = 0; c < CCH; ++c) {
        const float* a = pxy + c * HW;
        const float* b = pxz + c * HW;
        const float* d = pyz + c * HW;
        float lz = vz[c*RES+z0]; lz += wz * (vz[c*RES+z1] - lz);
        float ly = vy[c*RES+y0]; ly += wy * (vy[c*RES+y1] - ly);
        float lx = vx[c*RES+x0]; lx += wx * (vx[c*RES+x1] - lx);
        const float fa = bilerp(a, y0*RES+x0, y0*RES+x1, y1*RES+x0, y1*RES+x1, wx, wy) * lz;
        const float fb = bilerp(b, z0*RES+x0, z0*RES+x1, z1*RES+x0, z1*RES+x1, wx, wz) * ly;
        const float fc = bilerp(d, z0*RES+y0, z0*RES+y1, z1*RES+y0, z1*RES+y1, wy, wz) * lx;
        #pragma unroll
        for (int f = 0; f < FD; ++f)
            acc[f] += fa * basis[c*FD+f] + fb * basis[(CCH+c)*FD+f] + fc * basis[(2*CCH+c)*FD+f];
    }
    float* op = out + i * FD;
    #pragma unroll
    for (int f = 0; f < FD; ++f) op[f] = acc[f];
}

extern "C" void kernel_launch(void* const* d_in, const int* in_sizes, int n_in,
                              void* d_out, int out_size, void* d_ws, size_t ws_size,
                              hipStream_t stream) {
    const float* pts   = (const float*)d_in[0];
    const float* pxy   = (const float*)d_in[1];
    const float* pyz   = (const float*)d_in[2];
    const float* pxz   = (const float*)d_in[3];
    const float* vx    = (const float*)d_in[4];
    const float* vy    = (const float*)d_in[5];
    const float* vz    = (const float*)d_in[6];
    const float* basis = (const float*)d_in[7];
    float* out = (float*)d_out;

    if (ws_size < WS_NEED) {
        vm_eval_fallback<<<NPTS / BLK, BLK, 0, stream>>>(pts, pxy, pyz, pxz, vx, vy, vz, basis, out);
        return;
    }

    uint8_t* w = (uint8_t*)d_ws;
    __half*   planesH = (__half*)(w + WS_PLANEH);
    __half*   linesH  = (__half*)(w + WS_LINEH);
    __half*   bfragH  = (__half*)(w + WS_BFRAG);
    unsigned* chist   = (unsigned*)(w + WS_CHIST);
    unsigned* cursor  = (unsigned*)(w + WS_CURSOR);
    float4*   sorted  = (float4*)(w + WS_SORTED);

    hipMemsetAsync(chist, 0, (size_t)NCELL * 4, stream);
    prep_kernel<<<SORT_BLOCKS + PLANE_BLOCKS + LINE_BLOCKS + 1, BLK, 0, stream>>>(
        pts, pxy, pxz, pyz, vx, vy, vz, basis, planesH, linesH, bfragH, chist);
    scan_kernel<<<1, 1024, 0, stream>>>(chist, cursor);
    scatter_kernel<<<SORT_BLOCKS, BLK, 0, stream>>>(pts, cursor, sorted);
    eval_kernel<<<NCELL, BLK, 0, stream>>>(sorted, planesH, linesH, bfragH, chist, cursor, out);
}

// Round 12
// 166.603 us; speedup vs baseline: 1.3423x; 1.3423x over previous
//
#include <hip/hip_runtime.h>
#include <hip/hip_fp16.h>
#include <stdint.h>

// VM-factorized voxel grid: N pts -> 48 feats (3 planes x 16ch) -> 27 outputs.
// Pipeline: memset hist(4096) -> prep (planes/lines -> fp16 channel-last, basis
// B-frags, 16^3 hist, 256 blocks) -> scan -> scatter (two-pass LDS rank, 256 blocks)
// -> eval: BLK=512 (8 waves, 24 waves/CU at 3 blocks/CU), one block per cell,
// plane patches in LDS (48.5KB), ds_read gathers, fp16 interp, mfma 32x32x16,
// direct coalesced stores from MFMA fragments.

constexpr int NPTS = 2097152;
constexpr int CCH  = 16;
constexpr int RES  = 320;
constexpr long long HW = (long long)RES * RES;   // 102400
constexpr int FD   = 27;
constexpr int BLK  = 256;
constexpr int EBLK = 512;                        // eval block
constexpr int CDIM = 16;
constexpr int NCELL = CDIM * CDIM * CDIM;        // 4096
constexpr int PATCH = 22;
constexpr int PP_U4 = PATCH * PATCH * 2;         // 968
constexpr int PL_U4 = 3 * PP_U4;                 // 2904
constexpr int LN_U4 = 3 * PATCH * 2;             // 132
constexpr int SORT_BLOCKS = 256;
constexpr int PTS_PER_SORT = NPTS / SORT_BLOCKS; // 8192
constexpr int SORT_G = PTS_PER_SORT / (BLK * 4); // 8

constexpr int PLANE_BLOCKS = 1200;               // 3 * 400
constexpr int LINE_BLOCKS = 4;

// ---- workspace layout (bytes), all 16B-aligned ----
constexpr size_t WS_PLANEH = 0;                                   // 9,830,400
constexpr size_t WS_LINEH  = WS_PLANEH + 3ull*HW*CCH*2;           // 30,720
constexpr size_t WS_BFRAG  = WS_LINEH + 3ull*RES*CCH*2;           // 3,072
constexpr size_t WS_CHIST  = WS_BFRAG + 3072;                     // 16,384
constexpr size_t WS_CURSOR = WS_CHIST + (size_t)NCELL*4;          // 16,384
constexpr size_t WS_SORTED = WS_CURSOR + (size_t)NCELL*4;         // N*16
constexpr size_t WS_NEED   = WS_SORTED + (size_t)NPTS*16;         // ~43.5 MB

typedef _Float16 half8 __attribute__((ext_vector_type(8)));
typedef float f32x16 __attribute__((ext_vector_type(16)));

// ---------------- helpers ----------------
__device__ __forceinline__ int cell_key16(float px, float py, float pz) {
    int cx = min(max((int)((px + 1.f) * 8.f), 0), 15);
    int cy = min(max((int)((py + 1.f) * 8.f), 0), 15);
    int cz = min(max((int)((pz + 1.f) * 8.f), 0), 15);
    return (cz << 8) | (cy << 4) | cx;
}

// ---------------- prep: hist + planes/lines fp16 + basis B-frags ----------------
__global__ __launch_bounds__(BLK) void prep_kernel(
    const float* __restrict__ pts,
    const float* __restrict__ pxy, const float* __restrict__ pxz, const float* __restrict__ pyz,
    const float* __restrict__ vx, const float* __restrict__ vy, const float* __restrict__ vz,
    const float* __restrict__ basis,
    __half* __restrict__ planesH, __half* __restrict__ linesH, __half* __restrict__ bfragH,
    unsigned* __restrict__ chist) {
    __shared__ unsigned lh[NCELL];
    const int bid = blockIdx.x;
    const int tid = threadIdx.x;
    if (bid < SORT_BLOCKS) {                // histogram, 8192 pts/block
        #pragma unroll
        for (int k = 0; k < NCELL / BLK; ++k) lh[tid + k * BLK] = 0u;
        __syncthreads();
        const float4* p4 = ((const float4*)pts) + (size_t)bid * (PTS_PER_SORT * 3 / 4);
        #pragma unroll
        for (int g = 0; g < SORT_G; ++g) {
            const int t = g * BLK + tid;
            const float4 a = p4[t*3+0], b = p4[t*3+1], c = p4[t*3+2];
            atomicAdd(&lh[cell_key16(a.x, a.y, a.z)], 1u);
            atomicAdd(&lh[cell_key16(a.w, b.x, b.y)], 1u);
            atomicAdd(&lh[cell_key16(b.z, b.w, c.x)], 1u);
            atomicAdd(&lh[cell_key16(c.y, c.z, c.w)], 1u);
        }
        __syncthreads();
        #pragma unroll
        for (int k = 0; k < NCELL / BLK; ++k) {
            const int i = tid + k * BLK;
            if (lh[i]) atomicAdd(&chist[i], lh[i]);
        }
    } else if (bid < SORT_BLOCKS + PLANE_BLOCKS) {   // planes -> fp16 channel-last
        const int pb = bid - SORT_BLOCKS;
        const int plane = pb / 400;
        const int texel = (pb % 400) * BLK + tid;
        const float* src = (plane == 0) ? pxy : (plane == 1 ? pxz : pyz);
        union { ushort u[16]; uint4 q[2]; } pk;
        #pragma unroll
        for (int c = 0; c < CCH; ++c)
            pk.u[c] = __half_as_ushort(__float2half(src[(size_t)c * HW + texel]));
        uint4* dst = (uint4*)(planesH + ((size_t)plane * HW + texel) * CCH);
        dst[0] = pk.q[0]; dst[1] = pk.q[1];
    } else if (bid < SORT_BLOCKS + PLANE_BLOCKS + LINE_BLOCKS) {  // lines
        const int idx = (bid - SORT_BLOCKS - PLANE_BLOCKS) * BLK + tid;
        if (idx >= 3 * RES) return;
        const int axis = idx / RES, t = idx % RES;
        const float* src = (axis == 0) ? vx : (axis == 1 ? vy : vz);
        union { ushort u[16]; uint4 q[2]; } pk;
        #pragma unroll
        for (int c = 0; c < CCH; ++c)
            pk.u[c] = __half_as_ushort(__float2half(src[c * RES + t]));
        uint4* dst = (uint4*)(linesH + ((size_t)axis * RES + t) * CCH);
        dst[0] = pk.q[0]; dst[1] = pk.q[1];
    } else {   // basis (48,27) -> MFMA B-frag fp16
        if (tid < 192) {
            const int r = tid >> 6, l = tid & 63;
            const int col = l & 31, kb = l >> 5;
            __half* dst = bfragH + tid * 8;
            #pragma unroll
            for (int j = 0; j < 8; ++j) {
                float v = (col < FD) ? basis[(r * 16 + kb * 8 + j) * FD + col] : 0.f;
                dst[j] = __float2half(v);
            }
        }
    }
}

// ---------------- scan: exclusive scan of 4096 counts -> cursor ----------------
__global__ __launch_bounds__(1024) void scan_kernel(const unsigned* __restrict__ chist,
                                                    unsigned* __restrict__ cursor) {
    __shared__ unsigned lsum[1024];
    const int t = threadIdx.x;
    const uint4 v = ((const uint4*)chist)[t];
    const unsigned run = v.x + v.y + v.z + v.w;
    lsum[t] = run;
    __syncthreads();
    for (int o = 1; o < 1024; o <<= 1) {
        unsigned u = (t >= o) ? lsum[t - o] : 0u;
        __syncthreads();
        lsum[t] += u;
        __syncthreads();
    }
    const unsigned b = lsum[t] - run;
    ((uint4*)cursor)[t] = make_uint4(b, b + v.x, b + v.x + v.y, b + v.x + v.y + v.z);
}

// ---------------- scatter: two-pass LDS rank + 1 global atomic per (block,cell) ----------------
__global__ __launch_bounds__(BLK) void scatter_kernel(const float* __restrict__ pts,
                                                      unsigned* __restrict__ cursor,
                                                      float4* __restrict__ sorted) {
    __shared__ unsigned lh[NCELL];
    __shared__ unsigned lh2[NCELL];
    __shared__ unsigned lb[NCELL];
    const int bid = blockIdx.x;
    const int tid = threadIdx.x;
    #pragma unroll
    for (int k = 0; k < NCELL / BLK; ++k) { lh[tid + k*BLK] = 0u; lh2[tid + k*BLK] = 0u; }
    __syncthreads();
    const float4* p4 = ((const float4*)pts) + (size_t)bid * (PTS_PER_SORT * 3 / 4);
    #pragma unroll
    for (int g = 0; g < SORT_G; ++g) {       // pass 1: count
        const int t = g * BLK + tid;
        const float4 a = p4[t*3+0], b = p4[t*3+1], c = p4[t*3+2];
        atomicAdd(&lh[cell_key16(a.x, a.y, a.z)], 1u);
        atomicAdd(&lh[cell_key16(a.w, b.x, b.y)], 1u);
        atomicAdd(&lh[cell_key16(b.z, b.w, c.x)], 1u);
        atomicAdd(&lh[cell_key16(c.y, c.z, c.w)], 1u);
    }
    __syncthreads();
    #pragma unroll
    for (int k = 0; k < NCELL / BLK; ++k) {  // claim contiguous runs
        const int i = tid + k * BLK;
        lb[i] = lh[i] ? atomicAdd(&cursor[i], lh[i]) : 0u;
    }
    __syncthreads();
    const int ibase = bid * PTS_PER_SORT;
    #pragma unroll
    for (int g = 0; g < SORT_G; ++g) {       // pass 2: rank + place
        const int t = g * BLK + tid;
        const float4 a = p4[t*3+0], b = p4[t*3+1], c = p4[t*3+2];
        const int i0 = ibase + t * 4;
        int k; unsigned r;
        k = cell_key16(a.x, a.y, a.z); r = atomicAdd(&lh2[k], 1u);
        sorted[lb[k] + r] = make_float4(a.x, a.y, a.z, __int_as_float(i0 + 0));
        k = cell_key16(a.w, b.x, b.y); r = atomicAdd(&lh2[k], 1u);
        sorted[lb[k] + r] = make_float4(a.w, b.x, b.y, __int_as_float(i0 + 1));
        k = cell_key16(b.z, b.w, c.x); r = atomicAdd(&lh2[k], 1u);
        sorted[lb[k] + r] = make_float4(b.z, b.w, c.x, __int_as_float(i0 + 2));
        k = cell_key16(c.y, c.z, c.w); r = atomicAdd(&lh2[k], 1u);
        sorted[lb[k] + r] = make_float4(c.y, c.z, c.w, __int_as_float(i0 + 3));
    }
}

// ---------------- eval ----------------
__device__ __forceinline__ half8 interp8_lds(const uint4* __restrict__ sp,
                                             int i00, int i01, int i10, int i11,
                                             int il0, int il1,
                                             float wc, float wr, float lw) {
    union U { uint4 u; __half2 h2[4]; half8 v; };
    U c00, c01, c10, c11, la, lb, res;
    c00.u = sp[i00]; c01.u = sp[i01];
    c10.u = sp[i10]; c11.u = sp[i11];
    la.u  = sp[il0]; lb.u  = sp[il1];
    const float w00 = (1.f - wc) * (1.f - wr), w01 = wc * (1.f - wr);
    const float w10 = (1.f - wc) * wr,         w11 = wc * wr;
    const __half2 w00h = __float2half2_rn(w00), w01h = __float2half2_rn(w01);
    const __half2 w10h = __float2half2_rn(w10), w11h = __float2half2_rn(w11);
    const __half2 lwh  = __float2half2_rn(lw),  mlwh = __float2half2_rn(1.f - lw);
    #pragma unroll
    for (int q = 0; q < 4; ++q) {
        __half2 s = __hmul2(c00.h2[q], w00h);
        s = __hfma2(c01.h2[q], w01h, s);
        s = __hfma2(c10.h2[q], w10h, s);
        s = __hfma2(c11.h2[q], w11h, s);
        __half2 l = __hmul2(la.h2[q], mlwh);
        l = __hfma2(lb.h2[q], lwh, l);
        res.h2[q] = __hmul2(s, l);
    }
    return res.v;
}

__global__ __launch_bounds__(EBLK) void eval_kernel(
    const float4* __restrict__ sorted,
    const __half* __restrict__ planesH,
    const __half* __restrict__ linesH,
    const __half* __restrict__ bfragH,
    const unsigned* __restrict__ chist,
    const unsigned* __restrict__ cursor,
    float* __restrict__ out) {
    __shared__ uint4 s_patch[PL_U4 + LN_U4];     // 48,576 B
    __shared__ int s_oi[EBLK];                   // 2 KB
    const int bid = blockIdx.x;
    const int tid = threadIdx.x;
    const int cell = (bid & 7) * (NCELL / 8) + (bid >> 3);   // contiguous cells per XCD
    const int cx = cell & 15, cy = (cell >> 4) & 15, cz = cell >> 8;
    const int bx = (cx * 319) >> 4, by = (cy * 319) >> 4, bz = (cz * 319) >> 4;

    // stage plane patches (22x22 texels x 16ch fp16 each)
    for (int i = tid; i < PL_U4; i += EBLK) {
        const int p = i / PP_U4, rem = i - p * PP_U4;
        const int r = rem / 44, c4 = rem - r * 44;
        const int tx = c4 >> 1, h = c4 & 1;
        const int rb = (p == 0) ? by : bz;
        const int cb = (p == 2) ? by : bx;
        const int gr = min(rb + r, RES - 1), gc = min(cb + tx, RES - 1);
        s_patch[i] = ((const uint4*)(planesH + ((size_t)p * HW + (size_t)gr * RES + gc) * CCH))[h];
    }
    // stage line segments
    for (int i = tid; i < LN_U4; i += EBLK) {
        const int a = i / 44, rem = i - a * 44;
        const int t = rem >> 1, h = rem & 1;
        const int ab = (a == 0) ? bx : (a == 1) ? by : bz;
        const int gt = min(ab + t, RES - 1);
        s_patch[PL_U4 + i] = ((const uint4*)(linesH + ((size_t)a * RES + gt) * CCH))[h];
    }

    const int wid = tid >> 6, lane = tid & 63;
    const int pcol = lane & 31, kb = lane >> 5;
    union BU { uint4 u; half8 h; } b0u, b1u, b2u;
    const uint4* bf = (const uint4*)bfragH;
    b0u.u = bf[lane]; b1u.u = bf[64 + lane]; b2u.u = bf[128 + lane];

    __syncthreads();

    const int cnt = (int)chist[cell];
    const int start = (int)cursor[cell] - cnt;   // cursor holds end offsets post-scatter

    for (int base = 0; base < cnt; base += EBLK) {
        const int tb = wid * 64 + ((lane & 32) ? 0 : 0); // (wave tile base computed below)
        #pragma unroll
        for (int t = 0; t < 2; ++t) {
            const int tile = wid * 64 + t * 32;
            if (base + tile < cnt) {
                const int slot = base + tile + pcol;
                const float4 pt = sorted[start + min(slot, cnt - 1)];
                if (kb == 0) s_oi[tile + pcol] = __float_as_int(pt.w);

                const float scl = 0.5f * (RES - 1);
                const float fx = (pt.x + 1.f) * scl, fy = (pt.y + 1.f) * scl, fz = (pt.z + 1.f) * scl;
                const float xf = floorf(fx), yf = floorf(fy), zf = floorf(fz);
                const float wx = fx - xf, wy = fy - yf, wz = fz - zf;
                int x0 = min(max((int)xf, 0), RES - 1);
                int y0 = min(max((int)yf, 0), RES - 1);
                int z0 = min(max((int)zf, 0), RES - 1);
                const int x1 = min(x0 + 1, RES - 1);
                const int y1 = min(y0 + 1, RES - 1);
                const int z1 = min(z0 + 1, RES - 1);
                const int lx0 = x0 - bx, lx1 = x1 - bx;
                const int ly0 = y0 - by, ly1 = y1 - by;
                const int lz0 = z0 - bz, lz1 = z1 - bz;

                f32x16 acc;
                #pragma unroll
                for (int r = 0; r < 16; ++r) acc[r] = 0.f;

                half8 a0 = interp8_lds(s_patch,
                    (ly0*PATCH + lx0)*2 + kb, (ly0*PATCH + lx1)*2 + kb,
                    (ly1*PATCH + lx0)*2 + kb, (ly1*PATCH + lx1)*2 + kb,
                    PL_U4 + 2*44 + lz0*2 + kb, PL_U4 + 2*44 + lz1*2 + kb, wx, wy, wz);
                acc = __builtin_amdgcn_mfma_f32_32x32x16_f16(a0, b0u.h, acc, 0, 0, 0);
                half8 a1 = interp8_lds(s_patch,
                    PP_U4 + (lz0*PATCH + lx0)*2 + kb, PP_U4 + (lz0*PATCH + lx1)*2 + kb,
                    PP_U4 + (lz1*PATCH + lx0)*2 + kb, PP_U4 + (lz1*PATCH + lx1)*2 + kb,
                    PL_U4 + 1*44 + ly0*2 + kb, PL_U4 + 1*44 + ly1*2 + kb, wx, wz, wy);
                acc = __builtin_amdgcn_mfma_f32_32x32x16_f16(a1, b1u.h, acc, 0, 0, 0);
                half8 a2 = interp8_lds(s_patch,
                    2*PP_U4 + (lz0*PATCH + ly0)*2 + kb, 2*PP_U4 + (lz0*PATCH + ly1)*2 + kb,
                    2*PP_U4 + (lz1*PATCH + ly0)*2 + kb, 2*PP_U4 + (lz1*PATCH + ly1)*2 + kb,
                    PL_U4 + 0*44 + lx0*2 + kb, PL_U4 + 0*44 + lx1*2 + kb, wy, wz, wx);
                acc = __builtin_amdgcn_mfma_f32_32x32x16_f16(a2, b2u.h, acc, 0, 0, 0);

                // direct coalesced stores: D col=lane&31, row=(r&3)+8*(r>>2)+4*kb
                if (pcol < FD) {
                    #pragma unroll
                    for (int r = 0; r < 16; ++r) {
                        const int row = (r & 3) + 8 * (r >> 2) + 4 * kb;
                        if (base + tile + row < cnt) {
                            const int o = s_oi[tile + row];
                            out[(size_t)o * FD + pcol] = acc[r];
                        }
                    }
                }
            }
        }
    }
}

// ---------------- fallback (no workspace) ----------------
__device__ __forceinline__ float bilerp(const float* __restrict__ p,
                                        int o00, int o01, int o10, int o11,
                                        float wc, float wr) {
    float v00 = p[o00], v01 = p[o01], v10 = p[o10], v11 = p[o11];
    float top = v00 + wc * (v01 - v00);
    float bot = v10 + wc * (v11 - v10);
    return top + wr * (bot - top);
}

__global__ __launch_bounds__(BLK) void vm_eval_fallback(
    const float* __restrict__ pts,
    const float* __restrict__ pxy, const float* __restrict__ pyz, const float* __restrict__ pxz,
    const float* __restrict__ vx, const float* __restrict__ vy, const float* __restrict__ vz,
    const float* __restrict__ basis, float* __restrict__ out) {
    const long long i = (long long)blockIdx.x * BLK + threadIdx.x;
    const float px = pts[i*3], py = pts[i*3+1], pz = pts[i*3+2];
    const float scl = 0.5f * (RES - 1);
    const float fx = (px + 1.f) * scl, fy = (py + 1.f) * scl, fz = (pz + 1.f) * scl;
    const float xf = floorf(fx), yf = floorf(fy), zf = floorf(fz);
    const float wx = fx - xf, wy = fy - yf, wz = fz - zf;
    int x0 = min(max((int)xf, 0), RES - 1);
    int y0 = min(max((int)yf, 0), RES - 1);
    int z0 = min(max((int)zf, 0), RES - 1);
    const int x1 = min(x0+1, RES-1), y1 = min(y0+1, RES-1), z1 = min(z0+1, RES-1);
    float acc[FD];
    #pragma unroll
    for (int f = 0; f < FD; ++f) acc[f] = 0.f;
    #pragma unroll 4
    for (int c = 0; c < CCH; ++c) {
        const float* a = pxy + c * HW;
        const float* b = pxz + c * HW;
        const float* d = pyz + c * HW;
        float lz = vz[c*RES+z0]; lz += wz * (vz[c*RES+z1] - lz);
        float ly = vy[c*RES+y0]; ly += wy * (vy[c*RES+y1] - ly);
        float lx = vx[c*RES+x0]; lx += wx * (vx[c*RES+x1] - lx);
        const float fa = bilerp(a, y0*RES+x0, y0*RES+x1, y1*RES+x0, y1*RES+x1, wx, wy) * lz;
        const float fb = bilerp(b, z0*RES+x0, z0*RES+x1, z1*RES+x0, z1*RES+x1, wx, wz) * ly;
        const float fc = bilerp(d, z0*RES+y0, z0*RES+y1, z1*RES+y0, z1*RES+y1, wy, wz) * lx;
        #pragma unroll
        for (int f = 0; f < FD; ++f)
            acc[f] += fa * basis[c*FD+f] + fb * basis[(CCH+c)*FD+f] + fc * basis[(2*CCH+c)*FD+f];
    }
    float* op = out + i * FD;
    #pragma unroll
    for (int f = 0; f < FD; ++f) op[f] = acc[f];
}

extern "C" void kernel_launch(void* const* d_in, const int* in_sizes, int n_in,
                              void* d_out, int out_size, void* d_ws, size_t ws_size,
                              hipStream_t stream) {
    const float* pts   = (const float*)d_in[0];
    const float* pxy   = (const float*)d_in[1];
    const float* pyz   = (const float*)d_in[2];
    const float* pxz   = (const float*)d_in[3];
    const float* vx    = (const float*)d_in[4];
    const float* vy    = (const float*)d_in[5];
    const float* vz    = (const float*)d_in[6];
    const float* basis = (const float*)d_in[7];
    float* out = (float*)d_out;

    if (ws_size < WS_NEED) {
        vm_eval_fallback<<<NPTS / BLK, BLK, 0, stream>>>(pts, pxy, pyz, pxz, vx, vy, vz, basis, out);
        return;
    }

    uint8_t* w = (uint8_t*)d_ws;
    __half*   planesH = (__half*)(w + WS_PLANEH);
    __half*   linesH  = (__half*)(w + WS_LINEH);
    __half*   bfragH  = (__half*)(w + WS_BFRAG);
    unsigned* chist   = (unsigned*)(w + WS_CHIST);
    unsigned* cursor  = (unsigned*)(w + WS_CURSOR);
    float4*   sorted  = (float4*)(w + WS_SORTED);

    hipMemsetAsync(chist, 0, (size_t)NCELL * 4, stream);
    prep_kernel<<<SORT_BLOCKS + PLANE_BLOCKS + LINE_BLOCKS + 1, BLK, 0, stream>>>(
        pts, pxy, pxz, pyz, vx, vy, vz, basis, planesH, linesH, bfragH, chist);
    scan_kernel<<<1, 1024, 0, stream>>>(chist, cursor);
    scatter_kernel<<<SORT_BLOCKS, BLK, 0, stream>>>(pts, cursor, sorted);
    eval_kernel<<<NCELL, EBLK, 0, stream>>>(sorted, planesH, linesH, bfragH, chist, cursor, out);
}

// Round 14
// 163.848 us; speedup vs baseline: 1.3648x; 1.0168x over previous
//
#include <hip/hip_runtime.h>
#include <hip/hip_fp16.h>
#include <stdint.h>

// VM-factorized voxel grid: N pts -> 48 feats (3 planes x 16ch) -> 27 outputs.
// Pipeline: memset hist(4096) -> prep (planes/lines -> fp16 channel-last, basis
// B-frags, 16^3 hist) -> scan -> scatter (two-pass LDS rank) -> eval: BLK=512,
// one block per cell, plane patches in LDS with CHANNEL-HALF-MAJOR layout
// (bank-spread for random ds_read_b128), fp16 interp, mfma 32x32x16,
// direct coalesced stores from MFMA fragments, __shfl (full-exec) for indices.

constexpr int NPTS = 2097152;
constexpr int CCH  = 16;
constexpr int RES  = 320;
constexpr long long HW = (long long)RES * RES;   // 102400
constexpr int FD   = 27;
constexpr int BLK  = 256;
constexpr int EBLK = 512;                        // eval block
constexpr int CDIM = 16;
constexpr int NCELL = CDIM * CDIM * CDIM;        // 4096
constexpr int PATCH = 22;
constexpr int PP_HALF = PATCH * PATCH;           // 484 u4 per half
constexpr int PP_U4 = PP_HALF * 2;               // 968
constexpr int PL_U4 = 3 * PP_U4;                 // 2904
constexpr int LN_U4 = 3 * PATCH * 2;             // 132
constexpr int SORT_BLOCKS = 256;
constexpr int PTS_PER_SORT = NPTS / SORT_BLOCKS; // 8192
constexpr int SORT_G = PTS_PER_SORT / (BLK * 4); // 8

constexpr int PLANE_BLOCKS = 1200;               // 3 * 400
constexpr int LINE_BLOCKS = 4;

// ---- workspace layout (bytes), all 16B-aligned ----
constexpr size_t WS_PLANEH = 0;                                   // 9,830,400
constexpr size_t WS_LINEH  = WS_PLANEH + 3ull*HW*CCH*2;           // 30,720
constexpr size_t WS_BFRAG  = WS_LINEH + 3ull*RES*CCH*2;           // 3,072
constexpr size_t WS_CHIST  = WS_BFRAG + 3072;                     // 16,384
constexpr size_t WS_CURSOR = WS_CHIST + (size_t)NCELL*4;          // 16,384
constexpr size_t WS_SORTED = WS_CURSOR + (size_t)NCELL*4;         // N*16
constexpr size_t WS_NEED   = WS_SORTED + (size_t)NPTS*16;         // ~43.5 MB

typedef _Float16 half8 __attribute__((ext_vector_type(8)));
typedef float f32x16 __attribute__((ext_vector_type(16)));

// ---------------- helpers ----------------
__device__ __forceinline__ int cell_key16(float px, float py, float pz) {
    int cx = min(max((int)((px + 1.f) * 8.f), 0), 15);
    int cy = min(max((int)((py + 1.f) * 8.f), 0), 15);
    int cz = min(max((int)((pz + 1.f) * 8.f), 0), 15);
    return (cz << 8) | (cy << 4) | cx;
}

// ---------------- prep: hist + planes/lines fp16 + basis B-frags ----------------
__global__ __launch_bounds__(BLK) void prep_kernel(
    const float* __restrict__ pts,
    const float* __restrict__ pxy, const float* __restrict__ pxz, const float* __restrict__ pyz,
    const float* __restrict__ vx, const float* __restrict__ vy, const float* __restrict__ vz,
    const float* __restrict__ basis,
    __half* __restrict__ planesH, __half* __restrict__ linesH, __half* __restrict__ bfragH,
    unsigned* __restrict__ chist) {
    __shared__ unsigned lh[NCELL];
    const int bid = blockIdx.x;
    const int tid = threadIdx.x;
    if (bid < SORT_BLOCKS) {                // histogram, 8192 pts/block
        #pragma unroll
        for (int k = 0; k < NCELL / BLK; ++k) lh[tid + k * BLK] = 0u;
        __syncthreads();
        const float4* p4 = ((const float4*)pts) + (size_t)bid * (PTS_PER_SORT * 3 / 4);
        #pragma unroll
        for (int g = 0; g < SORT_G; ++g) {
            const int t = g * BLK + tid;
            const float4 a = p4[t*3+0], b = p4[t*3+1], c = p4[t*3+2];
            atomicAdd(&lh[cell_key16(a.x, a.y, a.z)], 1u);
            atomicAdd(&lh[cell_key16(a.w, b.x, b.y)], 1u);
            atomicAdd(&lh[cell_key16(b.z, b.w, c.x)], 1u);
            atomicAdd(&lh[cell_key16(c.y, c.z, c.w)], 1u);
        }
        __syncthreads();
        #pragma unroll
        for (int k = 0; k < NCELL / BLK; ++k) {
            const int i = tid + k * BLK;
            if (lh[i]) atomicAdd(&chist[i], lh[i]);
        }
    } else if (bid < SORT_BLOCKS + PLANE_BLOCKS) {   // planes -> fp16 channel-last
        const int pb = bid - SORT_BLOCKS;
        const int plane = pb / 400;
        const int texel = (pb % 400) * BLK + tid;
        const float* src = (plane == 0) ? pxy : (plane == 1 ? pxz : pyz);
        union { ushort u[16]; uint4 q[2]; } pk;
        #pragma unroll
        for (int c = 0; c < CCH; ++c)
            pk.u[c] = __half_as_ushort(__float2half(src[(size_t)c * HW + texel]));
        uint4* dst = (uint4*)(planesH + ((size_t)plane * HW + texel) * CCH);
        dst[0] = pk.q[0]; dst[1] = pk.q[1];
    } else if (bid < SORT_BLOCKS + PLANE_BLOCKS + LINE_BLOCKS) {  // lines
        const int idx = (bid - SORT_BLOCKS - PLANE_BLOCKS) * BLK + tid;
        if (idx >= 3 * RES) return;
        const int axis = idx / RES, t = idx % RES;
        const float* src = (axis == 0) ? vx : (axis == 1 ? vy : vz);
        union { ushort u[16]; uint4 q[2]; } pk;
        #pragma unroll
        for (int c = 0; c < CCH; ++c)
            pk.u[c] = __half_as_ushort(__float2half(src[c * RES + t]));
        uint4* dst = (uint4*)(linesH + ((size_t)axis * RES + t) * CCH);
        dst[0] = pk.q[0]; dst[1] = pk.q[1];
    } else {   // basis (48,27) -> MFMA B-frag fp16
        if (tid < 192) {
            const int r = tid >> 6, l = tid & 63;
            const int col = l & 31, kb = l >> 5;
            __half* dst = bfragH + tid * 8;
            #pragma unroll
            for (int j = 0; j < 8; ++j) {
                float v = (col < FD) ? basis[(r * 16 + kb * 8 + j) * FD + col] : 0.f;
                dst[j] = __float2half(v);
            }
        }
    }
}

// ---------------- scan: exclusive scan of 4096 counts -> cursor ----------------
__global__ __launch_bounds__(1024) void scan_kernel(const unsigned* __restrict__ chist,
                                                    unsigned* __restrict__ cursor) {
    __shared__ unsigned lsum[1024];
    const int t = threadIdx.x;
    const uint4 v = ((const uint4*)chist)[t];
    const unsigned run = v.x + v.y + v.z + v.w;
    lsum[t] = run;
    __syncthreads();
    for (int o = 1; o < 1024; o <<= 1) {
        unsigned u = (t >= o) ? lsum[t - o] : 0u;
        __syncthreads();
        lsum[t] += u;
        __syncthreads();
    }
    const unsigned b = lsum[t] - run;
    ((uint4*)cursor)[t] = make_uint4(b, b + v.x, b + v.x + v.y, b + v.x + v.y + v.z);
}

// ---------------- scatter: two-pass LDS rank + 1 global atomic per (block,cell) ----------------
__global__ __launch_bounds__(BLK) void scatter_kernel(const float* __restrict__ pts,
                                                      unsigned* __restrict__ cursor,
                                                      float4* __restrict__ sorted) {
    __shared__ unsigned lh[NCELL];
    __shared__ unsigned lh2[NCELL];
    __shared__ unsigned lb[NCELL];
    const int bid = blockIdx.x;
    const int tid = threadIdx.x;
    #pragma unroll
    for (int k = 0; k < NCELL / BLK; ++k) { lh[tid + k*BLK] = 0u; lh2[tid + k*BLK] = 0u; }
    __syncthreads();
    const float4* p4 = ((const float4*)pts) + (size_t)bid * (PTS_PER_SORT * 3 / 4);
    #pragma unroll
    for (int g = 0; g < SORT_G; ++g) {       // pass 1: count
        const int t = g * BLK + tid;
        const float4 a = p4[t*3+0], b = p4[t*3+1], c = p4[t*3+2];
        atomicAdd(&lh[cell_key16(a.x, a.y, a.z)], 1u);
        atomicAdd(&lh[cell_key16(a.w, b.x, b.y)], 1u);
        atomicAdd(&lh[cell_key16(b.z, b.w, c.x)], 1u);
        atomicAdd(&lh[cell_key16(c.y, c.z, c.w)], 1u);
    }
    __syncthreads();
    #pragma unroll
    for (int k = 0; k < NCELL / BLK; ++k) {  // claim contiguous runs
        const int i = tid + k * BLK;
        lb[i] = lh[i] ? atomicAdd(&cursor[i], lh[i]) : 0u;
    }
    __syncthreads();
    const int ibase = bid * PTS_PER_SORT;
    #pragma unroll
    for (int g = 0; g < SORT_G; ++g) {       // pass 2: rank + place
        const int t = g * BLK + tid;
        const float4 a = p4[t*3+0], b = p4[t*3+1], c = p4[t*3+2];
        const int i0 = ibase + t * 4;
        int k; unsigned r;
        k = cell_key16(a.x, a.y, a.z); r = atomicAdd(&lh2[k], 1u);
        sorted[lb[k] + r] = make_float4(a.x, a.y, a.z, __int_as_float(i0 + 0));
        k = cell_key16(a.w, b.x, b.y); r = atomicAdd(&lh2[k], 1u);
        sorted[lb[k] + r] = make_float4(a.w, b.x, b.y, __int_as_float(i0 + 1));
        k = cell_key16(b.z, b.w, c.x); r = atomicAdd(&lh2[k], 1u);
        sorted[lb[k] + r] = make_float4(b.z, b.w, c.x, __int_as_float(i0 + 2));
        k = cell_key16(c.y, c.z, c.w); r = atomicAdd(&lh2[k], 1u);
        sorted[lb[k] + r] = make_float4(c.y, c.z, c.w, __int_as_float(i0 + 3));
    }
}

// ---------------- eval ----------------
// Patch layout: s_patch[plane][half][texel] (u4). Lane reads its half (kb), so
// granule = texel mod 8 -> half-wave spreads over all 8 LDS 16B-granules.
__device__ __forceinline__ half8 interp8_lds(const uint4* __restrict__ sp,
                                             int i00, int i01, int i10, int i11,
                                             int il0, int il1,
                                             float wc, float wr, float lw) {
    union U { uint4 u; __half2 h2[4]; half8 v; };
    U c00, c01, c10, c11, la, lb, res;
    c00.u = sp[i00]; c01.u = sp[i01];
    c10.u = sp[i10]; c11.u = sp[i11];
    la.u  = sp[il0]; lb.u  = sp[il1];
    const float w00 = (1.f - wc) * (1.f - wr), w01 = wc * (1.f - wr);
    const float w10 = (1.f - wc) * wr,         w11 = wc * wr;
    const __half2 w00h = __float2half2_rn(w00), w01h = __float2half2_rn(w01);
    const __half2 w10h = __float2half2_rn(w10), w11h = __float2half2_rn(w11);
    const __half2 lwh  = __float2half2_rn(lw),  mlwh = __float2half2_rn(1.f - lw);
    #pragma unroll
    for (int q = 0; q < 4; ++q) {
        __half2 s = __hmul2(c00.h2[q], w00h);
        s = __hfma2(c01.h2[q], w01h, s);
        s = __hfma2(c10.h2[q], w10h, s);
        s = __hfma2(c11.h2[q], w11h, s);
        __half2 l = __hmul2(la.h2[q], mlwh);
        l = __hfma2(lb.h2[q], lwh, l);
        res.h2[q] = __hmul2(s, l);
    }
    return res.v;
}

__global__ __launch_bounds__(EBLK) void eval_kernel(
    const float4* __restrict__ sorted,
    const __half* __restrict__ planesH,
    const __half* __restrict__ linesH,
    const __half* __restrict__ bfragH,
    const unsigned* __restrict__ chist,
    const unsigned* __restrict__ cursor,
    float* __restrict__ out) {
    __shared__ uint4 s_patch[PL_U4 + LN_U4];     // 48,576 B
    const int bid = blockIdx.x;
    const int tid = threadIdx.x;
    const int cell = (bid & 7) * (NCELL / 8) + (bid >> 3);   // contiguous cells per XCD
    const int cx = cell & 15, cy = (cell >> 4) & 15, cz = cell >> 8;
    const int bx = (cx * 319) >> 4, by = (cy * 319) >> 4, bz = (cz * 319) >> 4;

    // stage plane patches, half-major: idx = p*968 + h*484 + (row*22 + col)
    for (int i = tid; i < PL_U4; i += EBLK) {
        const int p = i / PP_U4, rem = i - p * PP_U4;
        const int h = rem / PP_HALF, t = rem - h * PP_HALF;
        const int r = t / PATCH, tx = t - r * PATCH;
        const int rb = (p == 0) ? by : bz;
        const int cb = (p == 2) ? by : bx;
        const int gr = min(rb + r, RES - 1), gc = min(cb + tx, RES - 1);
        s_patch[i] = ((const uint4*)(planesH + ((size_t)p * HW + (size_t)gr * RES + gc) * CCH))[h];
    }
    // stage line segments, half-major: idx = PL_U4 + a*44 + h*22 + t
    for (int i = tid; i < LN_U4; i += EBLK) {
        const int a = i / 44, rem = i - a * 44;
        const int h = rem / PATCH, t = rem - h * PATCH;
        const int ab = (a == 0) ? bx : (a == 1) ? by : bz;
        const int gt = min(ab + t, RES - 1);
        s_patch[PL_U4 + i] = ((const uint4*)(linesH + ((size_t)a * RES + gt) * CCH))[h];
    }

    const int wid = tid >> 6, lane = tid & 63;
    const int pcol = lane & 31, kb = lane >> 5;
    union BU { uint4 u; half8 h; } b0u, b1u, b2u;
    const uint4* bf = (const uint4*)bfragH;
    b0u.u = bf[lane]; b1u.u = bf[64 + lane]; b2u.u = bf[128 + lane];

    const int khalf = kb * PP_HALF;       // plane half offset
    const int klin  = kb * PATCH;         // line half offset

    __syncthreads();

    const int cnt = (int)chist[cell];
    const int start = (int)cursor[cell] - cnt;   // cursor holds end offsets post-scatter

    for (int base = 0; base < cnt; base += EBLK) {
        #pragma unroll
        for (int t = 0; t < 2; ++t) {
            const int tile = wid * 64 + t * 32;
            if (base + tile < cnt) {
                const int slot = base + tile + pcol;
                const float4 pt = sorted[start + min(slot, cnt - 1)];
                const int oi = __float_as_int(pt.w);

                const float scl = 0.5f * (RES - 1);
                const float fx = (pt.x + 1.f) * scl, fy = (pt.y + 1.f) * scl, fz = (pt.z + 1.f) * scl;
                const float xf = floorf(fx), yf = floorf(fy), zf = floorf(fz);
                const float wx = fx - xf, wy = fy - yf, wz = fz - zf;
                int x0 = min(max((int)xf, 0), RES - 1);
                int y0 = min(max((int)yf, 0), RES - 1);
                int z0 = min(max((int)zf, 0), RES - 1);
                const int x1 = min(x0 + 1, RES - 1);
                const int y1 = min(y0 + 1, RES - 1);
                const int z1 = min(z0 + 1, RES - 1);
                const int lx0 = x0 - bx, lx1 = x1 - bx;
                const int ly0 = y0 - by, ly1 = y1 - by;
                const int lz0 = z0 - bz, lz1 = z1 - bz;

                f32x16 acc;
                #pragma unroll
                for (int r = 0; r < 16; ++r) acc[r] = 0.f;

                // plane xy (rows y, cols x) * line z
                half8 a0 = interp8_lds(s_patch,
                    khalf + ly0*PATCH + lx0, khalf + ly0*PATCH + lx1,
                    khalf + ly1*PATCH + lx0, khalf + ly1*PATCH + lx1,
                    PL_U4 + 2*44 + klin + lz0, PL_U4 + 2*44 + klin + lz1, wx, wy, wz);
                acc = __builtin_amdgcn_mfma_f32_32x32x16_f16(a0, b0u.h, acc, 0, 0, 0);
                // plane xz (rows z, cols x) * line y
                half8 a1 = interp8_lds(s_patch,
                    PP_U4 + khalf + lz0*PATCH + lx0, PP_U4 + khalf + lz0*PATCH + lx1,
                    PP_U4 + khalf + lz1*PATCH + lx0, PP_U4 + khalf + lz1*PATCH + lx1,
                    PL_U4 + 1*44 + klin + ly0, PL_U4 + 1*44 + klin + ly1, wx, wz, wy);
                acc = __builtin_amdgcn_mfma_f32_32x32x16_f16(a1, b1u.h, acc, 0, 0, 0);
                // plane yz (rows z, cols y) * line x
                half8 a2 = interp8_lds(s_patch,
                    2*PP_U4 + khalf + lz0*PATCH + ly0, 2*PP_U4 + khalf + lz0*PATCH + ly1,
                    2*PP_U4 + khalf + lz1*PATCH + ly0, 2*PP_U4 + khalf + lz1*PATCH + ly1,
                    PL_U4 + 0*44 + klin + lx0, PL_U4 + 0*44 + klin + lx1, wy, wz, wx);
                acc = __builtin_amdgcn_mfma_f32_32x32x16_f16(a2, b2u.h, acc, 0, 0, 0);

                // Gather output indices with FULL exec (shfl from disabled lanes is
                // undefined — caused the R13 failure), then do predicated stores.
                int orow[16];
                #pragma unroll
                for (int r = 0; r < 16; ++r) {
                    const int row = (r & 3) + 8 * (r >> 2) + 4 * kb;
                    orow[r] = __shfl(oi, row, 64);
                }
                // Direct coalesced stores: D col(=feature)=lane&31, row(=point) as above.
                if (pcol < FD) {
                    #pragma unroll
                    for (int r = 0; r < 16; ++r) {
                        const int row = (r & 3) + 8 * (r >> 2) + 4 * kb;
                        if (base + tile + row < cnt) {
                            out[(size_t)orow[r] * FD + pcol] = acc[r];
                        }
                    }
                }
            }
        }
    }
}

// ---------------- fallback (no workspace) ----------------
__device__ __forceinline__ float bilerp(const float* __restrict__ p,
                                        int o00, int o01, int o10, int o11,
                                        float wc, float wr) {
    float v00 = p[o00], v01 = p[o01], v10 = p[o10], v11 = p[o11];
    float top = v00 + wc * (v01 - v00);
    float bot = v10 + wc * (v11 - v10);
    return top + wr * (bot - top);
}

__global__ __launch_bounds__(BLK) void vm_eval_fallback(
    const float* __restrict__ pts,
    const float* __restrict__ pxy, const float* __restrict__ pyz, const float* __restrict__ pxz,
    const float* __restrict__ vx, const float* __restrict__ vy, const float* __restrict__ vz,
    const float* __restrict__ basis, float* __restrict__ out) {
    const long long i = (long long)blockIdx.x * BLK + threadIdx.x;
    const float px = pts[i*3], py = pts[i*3+1], pz = pts[i*3+2];
    const float scl = 0.5f * (RES - 1);
    const float fx = (px + 1.f) * scl, fy = (py + 1.f) * scl, fz = (pz + 1.f) * scl;
    const float xf = floorf(fx), yf = floorf(fy), zf = floorf(fz);
    const float wx = fx - xf, wy = fy - yf, wz = fz - zf;
    int x0 = min(max((int)xf, 0), RES - 1);
    int y0 = min(max((int)yf, 0), RES - 1);
    int z0 = min(max((int)zf, 0), RES - 1);
    const int x1 = min(x0+1, RES-1), y1 = min(y0+1, RES-1), z1 = min(z0+1, RES-1);
    float acc[FD];
    #pragma unroll
    for (int f = 0; f < FD; ++f) acc[f] = 0.f;
    #pragma unroll 4
    for (int c = 0; c < CCH; ++c) {
        const float* a = pxy + c * HW;
        const float* b = pxz + c * HW;
        const float* d = pyz + c * HW;
        float lz = vz[c*RES+z0]; lz += wz * (vz[c*RES+z1] - lz);
        float ly = vy[c*RES+y0]; ly += wy * (vy[c*RES+y1] - ly);
        float lx = vx[c*RES+x0]; lx += wx * (vx[c*RES+x1] - lx);
        const float fa = bilerp(a, y0*RES+x0, y0*RES+x1, y1*RES+x0, y1*RES+x1, wx, wy) * lz;
        const float fb = bilerp(b, z0*RES+x0, z0*RES+x1, z1*RES+x0, z1*RES+x1, wx, wz) * ly;
        const float fc = bilerp(d, z0*RES+y0, z0*RES+y1, z1*RES+y0, z1*RES+y1, wy, wz) * lx;
        #pragma unroll
        for (int f = 0; f < FD; ++f)
            acc[f] += fa * basis[c*FD+f] + fb * basis[(CCH+c)*FD+f] + fc * basis[(2*CCH+c)*FD+f];
    }
    float* op = out + i * FD;
    #pragma unroll
    for (int f = 0; f < FD; ++f) op[f] = acc[f];
}

extern "C" void kernel_launch(void* const* d_in, const int* in_sizes, int n_in,
                              void* d_out, int out_size, void* d_ws, size_t ws_size,
                              hipStream_t stream) {
    const float* pts   = (const float*)d_in[0];
    const float* pxy   = (const float*)d_in[1];
    const float* pyz   = (const float*)d_in[2];
    const float* pxz   = (const float*)d_in[3];
    const float* vx    = (const float*)d_in[4];
    const float* vy    = (const float*)d_in[5];
    const float* vz    = (const float*)d_in[6];
    const float* basis = (const float*)d_in[7];
    float* out = (float*)d_out;

    if (ws_size < WS_NEED) {
        vm_eval_fallback<<<NPTS / BLK, BLK, 0, stream>>>(pts, pxy, pyz, pxz, vx, vy, vz, basis, out);
        return;
    }

    uint8_t* w = (uint8_t*)d_ws;
    __half*   planesH = (__half*)(w + WS_PLANEH);
    __half*   linesH  = (__half*)(w + WS_LINEH);
    __half*   bfragH  = (__half*)(w + WS_BFRAG);
    unsigned* chist   = (unsigned*)(w + WS_CHIST);
    unsigned* cursor  = (unsigned*)(w + WS_CURSOR);
    float4*   sorted  = (float4*)(w + WS_SORTED);

    hipMemsetAsync(chist, 0, (size_t)NCELL * 4, stream);
    prep_kernel<<<SORT_BLOCKS + PLANE_BLOCKS + LINE_BLOCKS + 1, BLK, 0, stream>>>(
        pts, pxy, pxz, pyz, vx, vy, vz, basis, planesH, linesH, bfragH, chist);
    scan_kernel<<<1, 1024, 0, stream>>>(chist, cursor);
    scatter_kernel<<<SORT_BLOCKS, BLK, 0, stream>>>(pts, cursor, sorted);
    eval_kernel<<<NCELL, EBLK, 0, stream>>>(sorted, planesH, linesH, bfragH, chist, cursor, out);
}